// Round 1
// baseline (1853.434 us; speedup 1.0000x reference)
//
#include <hip/hip_runtime.h>
#include <hip/hip_bf16.h>

// Problem: T=256 timesteps, B=4096 batch, H=64.
// Phase 1 (k1_mlp): hid = relu(relu(x@Wr1+br1)@Wr2+br2)      [T*B,64] -> d_ws
// Phase 2 (k2_recur): per-batch-element serial LSTM over T steps, critic fused.
//   Batch elements are independent -> one wave owns 4 elements, no grid sync.
//   Whh and Wih live in LDS (interleaved [k][j][gate] so one ds_read_b128
//   feeds 16 FMAs across 4 elements). h broadcast via v_readlane (SGPR FMA).

#define TT 256
#define BB 4096
#define HHH 64
#define TBROWS (TT * BB)

__device__ __forceinline__ float bcastf(float v, int i) {
  return __int_as_float(__builtin_amdgcn_readlane(__float_as_int(v), i));
}
__device__ __forceinline__ float fsig(float x) { return 1.f / (1.f + __expf(-x)); }
__device__ __forceinline__ float ftanhf(float x) { return 1.f - 2.f / (__expf(2.f * x) + 1.f); }

template <typename T> __device__ __forceinline__ T to_xt(float v);
template <> __device__ __forceinline__ float to_xt<float>(float v) { return v; }
template <> __device__ __forceinline__ __hip_bfloat16 to_xt<__hip_bfloat16>(float v) { return __float2bfloat16(v); }
template <typename T> __device__ __forceinline__ float from_xt(T v);
template <> __device__ __forceinline__ float from_xt<float>(float v) { return v; }
template <> __device__ __forceinline__ float from_xt<__hip_bfloat16>(__hip_bfloat16 v) { return __bfloat162float(v); }

// ---------------- Phase 1: root MLP ----------------
template <typename XT>
__global__ __launch_bounds__(256) void k1_mlp(const float* __restrict__ x,
                                              const float* __restrict__ Wr1,
                                              const float* __restrict__ br1,
                                              const float* __restrict__ Wr2,
                                              const float* __restrict__ br2,
                                              XT* __restrict__ hid) {
  __shared__ float sWr1[9 * 32];
  __shared__ float sbr1[32];
  __shared__ float sWr2[32 * 64];
  __shared__ float sbr2[64];
  int tid = threadIdx.x;
  for (int i = tid; i < 288; i += 256) sWr1[i] = Wr1[i];
  if (tid < 32) sbr1[tid] = br1[tid];
  for (int i = tid; i < 2048; i += 256) sWr2[i] = Wr2[i];
  if (tid < 64) sbr2[tid] = br2[tid];
  __syncthreads();

  int lane = tid & 63;
  int wid = tid >> 6;
  int l = lane & 31;
  long gw = (long)blockIdx.x * 4 + wid;
  long nw = (long)gridDim.x * 4;
  for (long row0 = gw * 4; row0 < TBROWS; row0 += nw * 4) {
    // coalesced read of 4 rows of x (36 floats), broadcast via readlane
    float xl = 0.f;
    if (lane < 36) xl = x[row0 * 9 + lane];
    float h1r[4];
#pragma unroll
    for (int r = 0; r < 4; ++r) {
      float a = sbr1[l];
#pragma unroll
      for (int k = 0; k < 9; ++k) a = fmaf(bcastf(xl, r * 9 + k), sWr1[k * 32 + l], a);
      h1r[r] = fmaxf(a, 0.f);
    }
    float h2r[4];
#pragma unroll
    for (int r = 0; r < 4; ++r) h2r[r] = sbr2[lane];
#pragma unroll
    for (int i = 0; i < 32; ++i) {
      float w = sWr2[i * 64 + lane];
#pragma unroll
      for (int r = 0; r < 4; ++r) h2r[r] = fmaf(bcastf(h1r[r], i), w, h2r[r]);
    }
#pragma unroll
    for (int r = 0; r < 4; ++r) hid[(row0 + r) * 64 + lane] = to_xt<XT>(fmaxf(h2r[r], 0.f));
  }
}

// ---------------- Phase 2: recurrent LSTM + fused critic ----------------
// grid = 256 blocks x 256 threads (4 waves). Block b owns batch elems
// [b*16, b*16+16); each wave owns 4 elems for all 256 steps.
template <typename XT>
__global__ __launch_bounds__(256) void k2_recur(
    const XT* __restrict__ hid, const int* __restrict__ done,
    const float* __restrict__ h0, const float* __restrict__ c0,
    const float* __restrict__ Wih, const float* __restrict__ Whh,
    const float* __restrict__ bl,
    const float* __restrict__ Wc1, const float* __restrict__ bc1,
    const float* __restrict__ Wc2, const float* __restrict__ bc2,
    const float* __restrict__ Wc3, const float* __restrict__ bc3,
    float* __restrict__ out) {
  // interleaved: sW[k*256 + j*4 + g] = W[k*256 + g*64 + j]  (gate-last float4)
  __shared__ float sWih[64 * 256];
  __shared__ float sWhh[64 * 256];
  __shared__ float sbl[256];
  __shared__ float sWc1[64 * 16];
  __shared__ float sbc1[16];
  __shared__ float sWc2[16 * 8];
  __shared__ float sbc2[8];
  __shared__ float sWc3[8];
  __shared__ float hstage[4][4][68];  // [wave][elem][unit], padded -> no bank conflict

  int tid = threadIdx.x;
  for (int i = tid; i < 64 * 256; i += 256) {
    int k = i >> 8, r = i & 255, j = r >> 2, g = r & 3;
    sWih[i] = Wih[k * 256 + g * 64 + j];
    sWhh[i] = Whh[k * 256 + g * 64 + j];
  }
  for (int i = tid; i < 256; i += 256) {
    int j = i >> 2, g = i & 3;
    sbl[i] = bl[g * 64 + j];
  }
  for (int i = tid; i < 1024; i += 256) sWc1[i] = Wc1[i];
  if (tid < 128) sWc2[tid] = Wc2[tid];
  if (tid < 16) sbc1[tid] = bc1[tid];
  if (tid < 8) { sbc2[tid] = bc2[tid]; sWc3[tid] = Wc3[tid]; }
  __syncthreads();

  int lane = tid & 63;
  int wid = tid >> 6;
  int base_b = blockIdx.x * 16 + wid * 4;
  float bc3r = bc3[0];

  float h[4], c[4];
#pragma unroll
  for (int e = 0; e < 4; ++e) {
    h[e] = h0[(base_b + e) * 64 + lane];
    c[e] = c0[(base_b + e) * 64 + lane];
  }
  // prefetch t=0 inputs
  float hv[4];
  int dnv[4];
#pragma unroll
  for (int e = 0; e < 4; ++e) {
    hv[e] = from_xt(hid[(long)(base_b + e) * 64 + lane]);
    dnv[e] = done[base_b + e];
  }

  for (int t = 0; t < TT; ++t) {
    // episode-reset mask applied to incoming state
    float hm[4], hd[4];
#pragma unroll
    for (int e = 0; e < 4; ++e) {
      float m = 1.f - (float)dnv[e];
      hm[e] = h[e] * m;
      c[e] *= m;
      hd[e] = hv[e];
    }
    // prefetch next step (overlaps with matvec below)
    if (t + 1 < TT) {
#pragma unroll
      for (int e = 0; e < 4; ++e) {
        long row = (long)(t + 1) * BB + base_b + e;
        hv[e] = from_xt(hid[row * 64 + lane]);
        dnv[e] = done[row];
      }
    }
    // gates: acc[e] = b_lstm + hid@Wih + h@Whh   (lane j owns unit j, 4 gates)
    float4 acc[4];
#pragma unroll
    for (int e = 0; e < 4; ++e) acc[e] = ((const float4*)sbl)[lane];
#pragma unroll 16
    for (int k = 0; k < 64; ++k) {
      float4 wv = ((const float4*)sWih)[k * 64 + lane];
#pragma unroll
      for (int e = 0; e < 4; ++e) {
        float s = bcastf(hd[e], k);
        acc[e].x = fmaf(s, wv.x, acc[e].x);
        acc[e].y = fmaf(s, wv.y, acc[e].y);
        acc[e].z = fmaf(s, wv.z, acc[e].z);
        acc[e].w = fmaf(s, wv.w, acc[e].w);
      }
    }
#pragma unroll 16
    for (int k = 0; k < 64; ++k) {
      float4 wv = ((const float4*)sWhh)[k * 64 + lane];
#pragma unroll
      for (int e = 0; e < 4; ++e) {
        float s = bcastf(hm[e], k);
        acc[e].x = fmaf(s, wv.x, acc[e].x);
        acc[e].y = fmaf(s, wv.y, acc[e].y);
        acc[e].z = fmaf(s, wv.z, acc[e].z);
        acc[e].w = fmaf(s, wv.w, acc[e].w);
      }
    }
#pragma unroll
    for (int e = 0; e < 4; ++e) {
      float gi = fsig(acc[e].x);
      float gf = fsig(acc[e].y);
      float gg = ftanhf(acc[e].z);
      float go = fsig(acc[e].w);
      c[e] = fmaf(gf, c[e], gi * gg);
      h[e] = go * ftanhf(c[e]);
      hstage[wid][e][lane] = h[e];
    }
    __syncthreads();
    // fused critic: v = tanh(h@Wc1+bc1); v = tanh(v@Wc2+bc2); out = v@Wc3+bc3
    {
      int e2 = lane >> 4;
      int l16 = lane & 15;
      int gbase = lane & 48;
      const float* hrow = &hstage[wid][e2][0];
      float a1 = sbc1[l16];
#pragma unroll
      for (int k4 = 0; k4 < 16; ++k4) {
        float4 hh = *(const float4*)(hrow + k4 * 4);
        a1 = fmaf(hh.x, sWc1[(k4 * 4 + 0) * 16 + l16], a1);
        a1 = fmaf(hh.y, sWc1[(k4 * 4 + 1) * 16 + l16], a1);
        a1 = fmaf(hh.z, sWc1[(k4 * 4 + 2) * 16 + l16], a1);
        a1 = fmaf(hh.w, sWc1[(k4 * 4 + 3) * 16 + l16], a1);
      }
      float v1 = ftanhf(a1);
      float a2 = sbc2[lane & 7];
#pragma unroll
      for (int i = 0; i < 16; ++i)
        a2 = fmaf(__shfl(v1, gbase + i), sWc2[i * 8 + (lane & 7)], a2);
      float v2 = ftanhf(a2);
      float a3 = bc3r;
#pragma unroll
      for (int i = 0; i < 8; ++i)
        a3 = fmaf(__shfl(v2, gbase + i), sWc3[i], a3);
      if (l16 == 0) out[(long)t * BB + base_b + e2] = a3;
    }
    __syncthreads();
  }
}

extern "C" void kernel_launch(void* const* d_in, const int* in_sizes, int n_in,
                              void* d_out, int out_size, void* d_ws, size_t ws_size,
                              hipStream_t stream) {
  const float* x = (const float*)d_in[0];
  const int* done = (const int*)d_in[1];
  const float* h0 = (const float*)d_in[2];
  const float* c0 = (const float*)d_in[3];
  const float* Wr1 = (const float*)d_in[4];
  const float* br1 = (const float*)d_in[5];
  const float* Wr2 = (const float*)d_in[6];
  const float* br2 = (const float*)d_in[7];
  const float* Wih = (const float*)d_in[8];
  const float* Whh = (const float*)d_in[9];
  const float* bl = (const float*)d_in[10];
  const float* Wc1 = (const float*)d_in[11];
  const float* bc1 = (const float*)d_in[12];
  const float* Wc2 = (const float*)d_in[13];
  const float* bc2 = (const float*)d_in[14];
  const float* Wc3 = (const float*)d_in[15];
  const float* bc3 = (const float*)d_in[16];
  float* out = (float*)d_out;

  size_t need_f32 = (size_t)TBROWS * 64 * sizeof(float);
  if (ws_size >= need_f32) {
    float* hid = (float*)d_ws;
    k1_mlp<float><<<dim3(2048), dim3(256), 0, stream>>>(x, Wr1, br1, Wr2, br2, hid);
    k2_recur<float><<<dim3(256), dim3(256), 0, stream>>>(hid, done, h0, c0, Wih, Whh, bl,
                                                         Wc1, bc1, Wc2, bc2, Wc3, bc3, out);
  } else {
    __hip_bfloat16* hid = (__hip_bfloat16*)d_ws;
    k1_mlp<__hip_bfloat16><<<dim3(2048), dim3(256), 0, stream>>>(x, Wr1, br1, Wr2, br2, hid);
    k2_recur<__hip_bfloat16><<<dim3(256), dim3(256), 0, stream>>>(hid, done, h0, c0, Wih, Whh, bl,
                                                                  Wc1, bc1, Wc2, bc2, Wc3, bc3, out);
  }
}